// Round 1
// baseline (1586.015 us; speedup 1.0000x reference)
//
#include <hip/hip_runtime.h>
#include <hip/hip_bf16.h>
#include <stdint.h>

typedef __bf16 bf16_t;
typedef bf16_t bf16x8 __attribute__((ext_vector_type(8)));
typedef float f32x4 __attribute__((ext_vector_type(4)));

static constexpr int B_TOK  = 4096;
static constexpr int E_DIM  = 1024;
static constexpr int OUT_DIM= 256;
static constexpr int N_EXPC = 8;
static constexpr int HID    = 4096;
static constexpr int IMGSZ  = 4096;
static constexpr int NSLOT  = 2 * B_TOK;

#define DEVI __device__ __forceinline__

DEVI uint16_t f2bf(float f) {
  union { float f; uint32_t u; } v; v.f = f;
  uint32_t u = v.u;
  return (uint16_t)((u + 0x7FFFu + ((u >> 16) & 1u)) >> 16);
}

DEVI void gload_lds16(const void* g, void* l) {
  __builtin_amdgcn_global_load_lds((const __attribute__((address_space(1))) void*)g,
                                   (__attribute__((address_space(3))) void*)l, 16, 0, 0);
}

// ---------------- flat f32 -> bf16 convert ----------------
__global__ void cvt_bf16(const float* __restrict__ in, uint16_t* __restrict__ out, int n4)
{
  for (int i = blockIdx.x * blockDim.x + threadIdx.x; i < n4; i += gridDim.x * blockDim.x) {
    f32x4 v = *(const f32x4*)(in + (size_t)i * 4);
    ushort4 o;
    o.x = f2bf(v[0]); o.y = f2bf(v[1]); o.z = f2bf(v[2]); o.w = f2bf(v[3]);
    *(ushort4*)(out + (size_t)i * 4) = o;
  }
}

// ---------------- transpose + convert: in f32 [R][C] -> out bf16 [C][R] ----------------
__global__ void transpose_cvt(const float* __restrict__ in, uint16_t* __restrict__ out,
                              int R, int C)
{
  __shared__ __align__(16) float tile[32][33];
  size_t off = (size_t)blockIdx.z * (size_t)R * (size_t)C;
  const float* src = in + off;
  uint16_t* dst = out + off;
  int c0 = blockIdx.x * 32, r0 = blockIdx.y * 32;
  int tx = threadIdx.x, ty = threadIdx.y;   // block (32,8)
  #pragma unroll
  for (int i = 0; i < 32; i += 8)
    tile[ty + i][tx] = src[(size_t)(r0 + ty + i) * C + c0 + tx];
  __syncthreads();
  #pragma unroll
  for (int i = 0; i < 32; i += 8)
    dst[(size_t)(c0 + ty + i) * R + r0 + tx] = f2bf(tile[tx][ty + i]);
}

// ---------------- f32 GEMM (for gate fold, precision-critical): C = A[M,K] @ B[K,N] ----------------
__global__ __launch_bounds__(256)
void gemm_f32_64(const float* __restrict__ A, const float* __restrict__ B,
                 float* __restrict__ C, int M, int N, int K)
{
  __shared__ __align__(16) float sA[16][68];
  __shared__ __align__(16) float sB[16][68];
  int t = threadIdx.x;
  int tx = t & 15, ty = t >> 4;
  int m0 = blockIdx.x * 64, n0 = blockIdx.y * 64;
  float acc[4][4] = {};
  for (int k0 = 0; k0 < K; k0 += 16) {
    __syncthreads();
    {
      int k = t & 15, r = t >> 4;
      #pragma unroll
      for (int it = 0; it < 4; ++it)
        sA[k][r + 16 * it] = A[(size_t)(m0 + r + 16 * it) * K + k0 + k];
    }
    {
      int n = t & 63, k = t >> 6;
      #pragma unroll
      for (int it = 0; it < 4; ++it)
        sB[k + 4 * it][n] = B[(size_t)(k0 + k + 4 * it) * N + n0 + n];
    }
    __syncthreads();
    #pragma unroll
    for (int kk = 0; kk < 16; ++kk) {
      f32x4 a = *(const f32x4*)&sA[kk][ty * 4];
      f32x4 b = *(const f32x4*)&sB[kk][tx * 4];
      #pragma unroll
      for (int i = 0; i < 4; i++)
        #pragma unroll
        for (int j = 0; j < 4; j++)
          acc[i][j] = __builtin_fmaf(a[i], b[j], acc[i][j]);
    }
  }
  for (int i = 0; i < 4; i++)
    for (int j = 0; j < 4; j++)
      C[(size_t)(m0 + ty * 4 + i) * N + n0 + tx * 4 + j] = acc[i][j];
}

// ---------------- bf16 MFMA GEMM, m97-style 128xBN tile ----------------
// C[M,N] = A[M,K](bf16,row-major) @ BT[N,K](bf16,row-major)^T  (+bias, +activation)
// EPI: 0 = f32 store, 1 = bf16 store, 2 = silu->bf16, 3 = gelu(tanh)->bf16
template<int BN, int EPI, bool EXPERT, bool GATHER>
__global__ __launch_bounds__(256)
void gemm_tn(const uint16_t* __restrict__ A, int lda,
             const uint16_t* __restrict__ BT,
             void* __restrict__ Cv, int ldc,
             const float* __restrict__ bias,
             int M, int N, int K, int colOff,
             const int* __restrict__ counts, const int* __restrict__ bases,
             const int* __restrict__ perm,
             size_t bStride, int biasStride)
{
  constexpr int HN = BN / 2;
  constexpr int FN = BN / 32;
  int e = EXPERT ? (int)blockIdx.z : 0;
  int cnt = EXPERT ? counts[e] : M;
  int mt = blockIdx.x, nt = blockIdx.y;
  if (mt * 128 >= cnt) return;
  int rowBase = EXPERT ? bases[e] : 0;
  const uint16_t* Bt = BT + (EXPERT ? (size_t)e * bStride : 0);
  const float* bi = bias + (EXPERT ? (size_t)e * (size_t)biasStride : 0);

  __shared__ __align__(16) uint16_t sA[128 * 32];
  __shared__ __align__(16) uint16_t sB[BN * 32];

  int t = threadIdx.x;
  int wave = t >> 6, lane = t & 63;
  int wr = wave >> 1, wc = wave & 1;

  // staging rows for this thread (fixed across K loop)
  int r0 = (t >> 2), r1 = r0 + 64;
  int car0, car1;
  if (EXPERT) {
    int rr0 = mt * 128 + r0; if (rr0 > cnt - 1) rr0 = cnt - 1;
    int rr1 = mt * 128 + r1; if (rr1 > cnt - 1) rr1 = cnt - 1;
    if (GATHER) { car0 = perm[rowBase + rr0]; car1 = perm[rowBase + rr1]; }
    else        { car0 = rowBase + rr0;       car1 = rowBase + rr1; }
  } else {
    car0 = mt * 128 + r0; car1 = mt * 128 + r1;
  }
  const uint16_t* srcA0 = A + (size_t)car0 * lda + (t & 3) * 8;
  const uint16_t* srcA1 = A + (size_t)car1 * lda + (t & 3) * 8;
  const uint16_t* srcB0 = Bt + (size_t)(nt * BN + r0) * K + (t & 3) * 8;
  const uint16_t* srcB1 = Bt + (size_t)(nt * BN + r1) * K + (t & 3) * 8;

  char* ldsA = (char*)sA + wave * 1024;
  char* ldsB = (char*)sB + wave * 1024;

  f32x4 acc[4][FN];
  #pragma unroll
  for (int m = 0; m < 4; m++)
    #pragma unroll
    for (int n = 0; n < FN; n++)
      acc[m][n] = f32x4{0.f, 0.f, 0.f, 0.f};

  int fr = lane & 15, fkb = (lane >> 4) * 8;

  for (int kt = 0; kt < K; kt += 32) {
    __syncthreads();                 // protect previous iteration's LDS reads
    gload_lds16(srcA0 + kt, ldsA);
    gload_lds16(srcA1 + kt, ldsA + 4096);
    gload_lds16(srcB0 + kt, ldsB);
    if constexpr (BN == 128) gload_lds16(srcB1 + kt, ldsB + 4096);
    __syncthreads();                 // vmcnt(0) drain + barrier: staged data visible
    bf16x8 af[4], bfr[FN];
    #pragma unroll
    for (int m = 0; m < 4; m++)
      af[m] = *reinterpret_cast<const bf16x8*>(&sA[(wr * 64 + m * 16 + fr) * 32 + fkb]);
    #pragma unroll
    for (int n = 0; n < FN; n++)
      bfr[n] = *reinterpret_cast<const bf16x8*>(&sB[(wc * HN + n * 16 + fr) * 32 + fkb]);
    #pragma unroll
    for (int m = 0; m < 4; m++)
      #pragma unroll
      for (int n = 0; n < FN; n++)
        acc[m][n] = __builtin_amdgcn_mfma_f32_16x16x32_bf16(af[m], bfr[n], acc[m][n], 0, 0, 0);
  }

  // epilogue: C/D layout col=lane&15, row=(lane>>4)*4+reg (m89-verified)
  #pragma unroll
  for (int m = 0; m < 4; m++) {
    int lrow = wr * 64 + m * 16 + (lane >> 4) * 4;
    #pragma unroll
    for (int n = 0; n < FN; n++) {
      int col = nt * BN + wc * HN + n * 16 + (lane & 15);
      float bval = bi[col];
      #pragma unroll
      for (int r = 0; r < 4; r++) {
        int grow = mt * 128 + lrow + r;
        if (grow >= cnt) continue;
        float v = acc[m][n][r] + bval;
        if (EPI == 2) v = v / (1.f + __expf(-v));                        // silu
        if (EPI == 3) {                                                  // gelu tanh approx
          float z3 = v * v * v;
          v = 0.5f * v * (1.f + tanhf(0.7978845608028654f * (v + 0.044715f * z3)));
        }
        size_t cr = (size_t)(rowBase + grow) * ldc + colOff + col;
        if (EPI == 0) ((float*)Cv)[cr] = v;
        else          ((uint16_t*)Cv)[cr] = f2bf(v);
      }
    }
  }
}

// ---------------- gate-path fold helpers (all f32) ----------------
__global__ void bvwo_k(const float* __restrict__ bv, const float* __restrict__ Wo,
                       const float* __restrict__ bo, float* __restrict__ t1)
{
  int j = blockIdx.x * 256 + threadIdx.x;
  float s = 0.f;
  for (int k = 0; k < E_DIM; ++k) s = __builtin_fmaf(bv[k], Wo[(size_t)k * E_DIM + j], s);
  t1[j] = s + bo[j];
}

__global__ void g3_k(const float* __restrict__ G2, const float* __restrict__ Wg,
                     float* __restrict__ G3)
{
  int idx = blockIdx.x * 256 + threadIdx.x;   // 8192 = 1024*8
  int k = idx >> 3, e = idx & 7;
  float s = 0.f;
  for (int m = 0; m < E_DIM; ++m) s = __builtin_fmaf(G2[(size_t)k * E_DIM + m], Wg[m * 8 + e], s);
  G3[idx] = s;
}

__global__ void gbias_k(const float* __restrict__ t1, const float* __restrict__ Wg,
                        const float* __restrict__ bg, float* __restrict__ gb)
{
  int e = threadIdx.x;
  if (e < 8) {
    float s = 0.f;
    for (int k = 0; k < E_DIM; ++k) s = __builtin_fmaf(t1[k], Wg[k * 8 + e], s);
    gb[e] = s + bg[e];
  }
}

// ---------------- gate: logits -> softmax -> top2 -> counts ----------------
__global__ __launch_bounds__(256)
void gate_k(const float* __restrict__ text, const float* __restrict__ G3,
            const float* __restrict__ gb, float* __restrict__ gate_out,
            int* __restrict__ topIdx, float* __restrict__ topW,
            int* __restrict__ counts)
{
  __shared__ __align__(16) float sT[E_DIM];
  __shared__ float lg[8];
  int b = blockIdx.x, t = threadIdx.x;
  *(f32x4*)&sT[t * 4] = *(const f32x4*)&text[(size_t)b * E_DIM + t * 4];
  __syncthreads();
  int wave = t >> 6, lane = t & 63;
  #pragma unroll
  for (int ei = 0; ei < 2; ++ei) {
    int e = wave * 2 + ei;
    float s = 0.f;
    for (int k = lane; k < E_DIM; k += 64) s = __builtin_fmaf(sT[k], G3[k * 8 + e], s);
    #pragma unroll
    for (int off = 32; off; off >>= 1) s += __shfl_down(s, off);
    if (lane == 0) lg[e] = s + gb[e];
  }
  __syncthreads();
  if (t == 0) {
    float p[8];
    float mx = lg[0];
    for (int i = 1; i < 8; i++) mx = fmaxf(mx, lg[i]);
    float den = 0.f;
    for (int i = 0; i < 8; i++) { p[i] = __expf(lg[i] - mx); den += p[i]; }
    float inv = 1.f / den;
    for (int i = 0; i < 8; i++) { p[i] *= inv; gate_out[(size_t)b * 8 + i] = p[i]; }
    int i1 = 0;
    for (int i = 1; i < 8; i++) if (p[i] > p[i1]) i1 = i;       // ties -> lower index (strict >)
    int i2 = (i1 == 0) ? 1 : 0;
    for (int i = 0; i < 8; i++) if (i != i1 && p[i] > p[i2]) i2 = i;
    float ex = __expf(p[i2] - p[i1]);                            // softmax over the two top PROBS
    float w1 = 1.f / (1.f + ex), w2 = ex / (1.f + ex);
    topIdx[b * 2] = i1; topIdx[b * 2 + 1] = i2;
    topW[b * 2] = w1;  topW[b * 2 + 1] = w2;
    atomicAdd(&counts[i1], 1);
    atomicAdd(&counts[i2], 1);
  }
}

__global__ void imp_k(const float* __restrict__ gate_out, float* __restrict__ imp)
{
  int e = blockIdx.x, t = threadIdx.x;
  float s = 0.f;
  for (int b = t; b < B_TOK; b += 256) s += gate_out[(size_t)b * 8 + e];
  __shared__ float red[256];
  red[t] = s; __syncthreads();
  for (int off = 128; off; off >>= 1) { if (t < off) red[t] += red[t + off]; __syncthreads(); }
  if (t == 0) imp[e] = red[0];
}

__global__ void loss_k(const float* __restrict__ imp, float* __restrict__ out_loss)
{
  if (threadIdx.x == 0 && blockIdx.x == 0) {
    float m = 0.f;
    for (int e = 0; e < 8; e++) m += imp[e];
    m *= 0.125f;
    float v = 0.f;
    for (int e = 0; e < 8; e++) { float d = imp[e] - m; v += d * d; }
    v /= 7.f;                                  // ddof=1
    out_loss[0] = 0.01f * v / (m * m);
  }
}

__global__ void zero_k(int* counts, int* cursor)
{
  int t = threadIdx.x;
  if (t < 8) { counts[t] = 0; cursor[t] = 0; }
}

__global__ void scan_k(const int* __restrict__ counts, int* __restrict__ bases)
{
  if (threadIdx.x == 0) {
    int a = 0;
    for (int e = 0; e < 8; e++) { bases[e] = a; a += counts[e]; }
  }
}

__global__ void fill_k(const int* __restrict__ topIdx, int* __restrict__ cursor,
                       const int* __restrict__ bases, int* __restrict__ perm,
                       int* __restrict__ slotOf)
{
  int b = blockIdx.x * 256 + threadIdx.x;
  if (b < B_TOK) {
    #pragma unroll
    for (int j = 0; j < 2; j++) {
      int e = topIdx[b * 2 + j];
      int pos = atomicAdd(&cursor[e], 1);
      int slot = bases[e] + pos;
      perm[slot] = b;
      slotOf[b * 2 + j] = slot;
    }
  }
}

__global__ __launch_bounds__(256)
void combine_k(const float* __restrict__ Yg, const int* __restrict__ slotOf,
               const float* __restrict__ topW, float* __restrict__ y)
{
  int b = blockIdx.x, t = threadIdx.x;
  int s0 = slotOf[b * 2], s1 = slotOf[b * 2 + 1];
  float w0 = topW[b * 2], w1 = topW[b * 2 + 1];
  f32x4 a = *(const f32x4*)&Yg[(size_t)s0 * E_DIM + t * 4];
  f32x4 c = *(const f32x4*)&Yg[(size_t)s1 * E_DIM + t * 4];
  f32x4 r = a * w0 + c * w1;
  *(f32x4*)&y[(size_t)b * E_DIM + t * 4] = r;
}

// ---------------- host ----------------
extern "C" void kernel_launch(void* const* d_in, const int* in_sizes, int n_in,
                              void* d_out, int out_size, void* d_ws, size_t ws_size,
                              hipStream_t stream)
{
  (void)in_sizes; (void)n_in; (void)out_size;
  const float* src   = (const float*)d_in[0];
  const float* tgt   = (const float*)d_in[1];
  const float* bgr   = (const float*)d_in[2];
  const float* image = (const float*)d_in[3];
  const float* text  = (const float*)d_in[4];
  const float* W_enc = (const float*)d_in[5];
  const float* b_enc = (const float*)d_in[6];
  const float* W_img = (const float*)d_in[7];
  const float* b_img = (const float*)d_in[8];
  // d_in[9..12]: Wq,bq,Wk,bk — dead code (softmax over length-1 axis == 1)
  const float* Wv    = (const float*)d_in[13];
  const float* bv    = (const float*)d_in[14];
  const float* Wo    = (const float*)d_in[15];
  const float* bo    = (const float*)d_in[16];
  const float* Wg    = (const float*)d_in[17];
  const float* bgg   = (const float*)d_in[18];
  const float* W1    = (const float*)d_in[19];
  const float* b1    = (const float*)d_in[20];
  const float* W2    = (const float*)d_in[21];
  const float* b2    = (const float*)d_in[22];

  float* out_y    = (float*)d_out;
  float* out_gate = out_y + (size_t)B_TOK * E_DIM;
  float* out_loss = out_gate + (size_t)B_TOK * N_EXPC;

  char* p = (char*)d_ws;
  auto alloc = [&](size_t bytes) { char* r = p; p += (bytes + 255) & ~(size_t)255; return r; };
  uint16_t* WencT = (uint16_t*)alloc((size_t)OUT_DIM * IMGSZ * 2);
  uint16_t* WimgT = (uint16_t*)alloc((size_t)OUT_DIM * E_DIM * 2);
  uint16_t* W1T   = (uint16_t*)alloc((size_t)N_EXPC * HID * E_DIM * 2);
  uint16_t* W2T   = (uint16_t*)alloc((size_t)N_EXPC * E_DIM * HID * 2);
  float* G2   = (float*)alloc((size_t)E_DIM * E_DIM * 4);
  float* G3   = (float*)alloc((size_t)E_DIM * 8 * 4);
  float* t1   = (float*)alloc(E_DIM * 4);
  float* gbv  = (float*)alloc(64 * 4);
  int*   topIdx = (int*)alloc(B_TOK * 2 * 4);
  float* topW   = (float*)alloc(B_TOK * 2 * 4);
  int*   slotOf = (int*)alloc(B_TOK * 2 * 4);
  int*   counts = (int*)alloc(64 * 4);
  int*   bases  = (int*)alloc(64 * 4);
  int*   cursor = (int*)alloc(64 * 4);
  int*   perm   = (int*)alloc(NSLOT * 4);
  uint16_t* xbf   = (uint16_t*)alloc((size_t)B_TOK * E_DIM * 2);
  uint16_t* Abuf  = (uint16_t*)alloc((size_t)B_TOK * IMGSZ * 2);
  uint16_t* imgBf = (uint16_t*)alloc((size_t)B_TOK * E_DIM * 2);
  uint16_t* Hbuf  = (uint16_t*)alloc((size_t)NSLOT * HID * 2);
  float*    Yg    = (float*)alloc((size_t)NSLOT * E_DIM * 4);
  if ((size_t)(p - (char*)d_ws) > ws_size) return;   // ws too small: fail visibly (y stays 0)

  zero_k<<<1, 64, 0, stream>>>(counts, cursor);

  dim3 tb(32, 8);
  transpose_cvt<<<dim3(OUT_DIM / 32, IMGSZ / 32, 1), tb, 0, stream>>>(W_enc, WencT, IMGSZ, OUT_DIM);
  transpose_cvt<<<dim3(OUT_DIM / 32, E_DIM / 32, 1), tb, 0, stream>>>(W_img, WimgT, E_DIM, OUT_DIM);
  transpose_cvt<<<dim3(HID / 32, E_DIM / 32, 8), tb, 0, stream>>>(W1, W1T, E_DIM, HID);
  transpose_cvt<<<dim3(E_DIM / 32, HID / 32, 8), tb, 0, stream>>>(W2, W2T, HID, E_DIM);

  // gate fold (f32, precision-critical): logits = text @ (Wv@Wo@Wg) + ((bv@Wo+bo)@Wg + bg)
  gemm_f32_64<<<dim3(16, 16), 256, 0, stream>>>(Wv, Wo, G2, E_DIM, E_DIM, E_DIM);
  bvwo_k<<<4, 256, 0, stream>>>(bv, Wo, bo, t1);
  g3_k<<<32, 256, 0, stream>>>(G2, Wg, G3);
  gbias_k<<<1, 64, 0, stream>>>(t1, Wg, bgg, gbv);
  gate_k<<<B_TOK, 256, 0, stream>>>(text, G3, gbv, out_gate, topIdx, topW, counts);
  imp_k<<<8, 256, 0, stream>>>(out_gate, t1);
  loss_k<<<1, 64, 0, stream>>>(t1, out_loss);
  scan_k<<<1, 64, 0, stream>>>(counts, bases);
  fill_k<<<16, 256, 0, stream>>>(topIdx, cursor, bases, perm, slotOf);

  // visionFeatures x = [enc(s) | enc(t) | enc(bg) | silu(img@W_img+b)]  (bf16)
  const float* encIn[3] = { src, tgt, bgr };
  for (int ii = 0; ii < 3; ++ii) {
    cvt_bf16<<<2048, 256, 0, stream>>>(encIn[ii], Abuf, B_TOK * IMGSZ / 4);
    gemm_tn<64, 1, false, false><<<dim3(B_TOK / 128, OUT_DIM / 64), 256, 0, stream>>>(
        Abuf, IMGSZ, WencT, xbf, E_DIM, b_enc, B_TOK, OUT_DIM, IMGSZ, ii * 256,
        nullptr, nullptr, nullptr, 0, 0);
  }
  cvt_bf16<<<2048, 256, 0, stream>>>(image, imgBf, B_TOK * E_DIM / 4);
  gemm_tn<64, 2, false, false><<<dim3(B_TOK / 128, OUT_DIM / 64), 256, 0, stream>>>(
      imgBf, E_DIM, WimgT, xbf, E_DIM, b_img, B_TOK, OUT_DIM, E_DIM, 768,
      nullptr, nullptr, nullptr, 0, 0);

  // sparse top-2 expert MLPs
  gemm_tn<128, 3, true, true><<<dim3(B_TOK / 128, HID / 128, 8), 256, 0, stream>>>(
      xbf, E_DIM, W1T, Hbuf, HID, b1, B_TOK, HID, E_DIM, 0,
      counts, bases, perm, (size_t)HID * E_DIM, HID);
  gemm_tn<128, 0, true, false><<<dim3(B_TOK / 128, E_DIM / 128, 8), 256, 0, stream>>>(
      Hbuf, HID, W2T, Yg, E_DIM, b2, B_TOK, E_DIM, HID, 0,
      counts, bases, perm, (size_t)E_DIM * HID, E_DIM);

  combine_k<<<B_TOK, 256, 0, stream>>>(Yg, slotOf, topW, out_y);
}

// Round 2
// 1404.843 us; speedup vs baseline: 1.1290x; 1.1290x over previous
//
#include <hip/hip_runtime.h>
#include <hip/hip_bf16.h>
#include <stdint.h>

typedef __bf16 bf16_t;
typedef bf16_t bf16x8 __attribute__((ext_vector_type(8)));
typedef float f32x4 __attribute__((ext_vector_type(4)));
typedef uint16_t u16x8 __attribute__((ext_vector_type(8)));

static constexpr int B_TOK  = 4096;
static constexpr int E_DIM  = 1024;
static constexpr int OUT_DIM= 256;
static constexpr int N_EXPC = 8;
static constexpr int HID    = 4096;
static constexpr int IMGSZ  = 4096;
static constexpr int NSLOT  = 2 * B_TOK;

#define DEVI __device__ __forceinline__

DEVI uint16_t f2bf(float f) {
  union { float f; uint32_t u; } v; v.f = f;
  uint32_t u = v.u;
  return (uint16_t)((u + 0x7FFFu + ((u >> 16) & 1u)) >> 16);
}

DEVI u16x8 pack8(f32x4 a, f32x4 b) {
  u16x8 r;
  r[0] = f2bf(a[0]); r[1] = f2bf(a[1]); r[2] = f2bf(a[2]); r[3] = f2bf(a[3]);
  r[4] = f2bf(b[0]); r[5] = f2bf(b[1]); r[6] = f2bf(b[2]); r[7] = f2bf(b[3]);
  return r;
}

DEVI void gload_lds16(const void* g, void* l) {
  __builtin_amdgcn_global_load_lds((const __attribute__((address_space(1))) void*)g,
                                   (__attribute__((address_space(3))) void*)l, 16, 0, 0);
}

// ---------------- transpose + convert: in f32 [R][C] -> out bf16 [C][R] ----------------
__global__ void transpose_cvt(const float* __restrict__ in, uint16_t* __restrict__ out,
                              int R, int C)
{
  __shared__ __align__(16) float tile[32][33];
  size_t off = (size_t)blockIdx.z * (size_t)R * (size_t)C;
  const float* src = in + off;
  uint16_t* dst = out + off;
  int c0 = blockIdx.x * 32, r0 = blockIdx.y * 32;
  int tx = threadIdx.x, ty = threadIdx.y;   // block (32,8)
  #pragma unroll
  for (int i = 0; i < 32; i += 8)
    tile[ty + i][tx] = src[(size_t)(r0 + ty + i) * C + c0 + tx];
  __syncthreads();
  #pragma unroll
  for (int i = 0; i < 32; i += 8)
    dst[(size_t)(c0 + ty + i) * R + r0 + tx] = f2bf(tile[tx][ty + i]);
}

// ---------------- 128x128 bf16 MFMA GEMM, 2-phase double-buffered (T3-min) ----------------
// C[M,N] = A[M,K] @ BT[N,K]^T  (+bias, +activation)
// EPI: 0 = f32 store, 1 = bf16 store, 2 = silu->bf16, 3 = gelu(tanh)->bf16
// AF32: A is f32, reg-staged + converted to bf16 during ds_write (enc/img path).
template<int EPI, bool EXPERT, bool GATHER, bool AF32>
__global__ __launch_bounds__(256)
void gemm128(const float* __restrict__ Af0, const float* __restrict__ Af1,
             const float* __restrict__ Af2, const uint16_t* __restrict__ Ab,
             int lda,
             const uint16_t* __restrict__ BT,
             void* __restrict__ Cv, int ldc,
             const float* __restrict__ bias,
             int M, int N, int K, int colBase, int colStride,
             const int* __restrict__ counts, const int* __restrict__ bases,
             const int* __restrict__ perm, size_t bStride, int biasStride)
{
  int z = blockIdx.z;
  int e = EXPERT ? z : 0;
  int cnt = EXPERT ? counts[e] : M;
  int mt = blockIdx.x, nt = blockIdx.y;
  if (mt * 128 >= cnt) return;
  int rowBase = EXPERT ? bases[e] : 0;
  const uint16_t* Bt = BT + (EXPERT ? (size_t)e * bStride : 0);
  const float* bi = bias + (EXPERT ? (size_t)e * (size_t)biasStride : 0);
  int colOff = EXPERT ? 0 : colBase + z * colStride;

  __shared__ __align__(16) uint16_t sA[2][128 * 32];
  __shared__ __align__(16) uint16_t sB[2][128 * 32];

  int t = threadIdx.x, wave = t >> 6, lane = t & 63;
  int wr = wave >> 1, wc = wave & 1;

  int r0 = t >> 2, r1 = r0 + 64;
  int car0, car1;
  if (EXPERT) {
    int rr0 = mt * 128 + r0; if (rr0 > cnt - 1) rr0 = cnt - 1;
    int rr1 = mt * 128 + r1; if (rr1 > cnt - 1) rr1 = cnt - 1;
    if (GATHER) { car0 = perm[rowBase + rr0]; car1 = perm[rowBase + rr1]; }
    else        { car0 = rowBase + rr0;       car1 = rowBase + rr1; }
  } else {
    car0 = mt * 128 + r0; car1 = mt * 128 + r1;
  }

  const float *fA0 = nullptr, *fA1 = nullptr;
  const uint16_t *bA0 = nullptr, *bA1 = nullptr;
  if constexpr (AF32) {
    const float* Af = (z == 0) ? Af0 : (z == 1) ? Af1 : Af2;
    fA0 = Af + (size_t)car0 * lda + (t & 3) * 8;
    fA1 = Af + (size_t)car1 * lda + (t & 3) * 8;
  } else {
    bA0 = Ab + (size_t)car0 * lda + (t & 3) * 8;
    bA1 = Ab + (size_t)car1 * lda + (t & 3) * 8;
  }
  const uint16_t* pB0 = Bt + (size_t)(nt * 128 + r0) * K + (t & 3) * 8;
  const uint16_t* pB1 = Bt + (size_t)(nt * 128 + r1) * K + (t & 3) * 8;
  uint32_t aw0 = r0 * 32 + (t & 3) * 8;     // element offset of this thread's A slice
  uint32_t aw1 = r1 * 32 + (t & 3) * 8;

  f32x4 acc[4][4];
  #pragma unroll
  for (int m = 0; m < 4; m++)
    #pragma unroll
    for (int n = 0; n < 4; n++)
      acc[m][n] = f32x4{0.f, 0.f, 0.f, 0.f};

  int fr = lane & 15, fkb = (lane >> 4) * 8;
  int nk = K >> 5;
  f32x4 ra, rb, rc, rd;

  // prologue: stage kt=0 into buffer 0
  if constexpr (AF32) {
    ra = *(const f32x4*)(fA0);     rb = *(const f32x4*)(fA0 + 4);
    rc = *(const f32x4*)(fA1);     rd = *(const f32x4*)(fA1 + 4);
    *(u16x8*)&sA[0][aw0] = pack8(ra, rb);
    *(u16x8*)&sA[0][aw1] = pack8(rc, rd);
    gload_lds16(pB0, (char*)sB[0] + wave * 1024);
    gload_lds16(pB1, (char*)sB[0] + wave * 1024 + 4096);
  } else {
    gload_lds16(bA0, (char*)sA[0] + wave * 1024);
    gload_lds16(bA1, (char*)sA[0] + wave * 1024 + 4096);
    gload_lds16(pB0, (char*)sB[0] + wave * 1024);
    gload_lds16(pB1, (char*)sB[0] + wave * 1024 + 4096);
  }
  __syncthreads();

  int cur = 0;
  for (int kt = 0; kt < nk; ++kt) {
    bool more = (kt + 1 < nk);
    int ko = (kt + 1) << 5;
    if (more) {                           // issue next-tile stage BEFORE compute
      if constexpr (AF32) {
        ra = *(const f32x4*)(fA0 + ko);     rb = *(const f32x4*)(fA0 + ko + 4);
        rc = *(const f32x4*)(fA1 + ko);     rd = *(const f32x4*)(fA1 + ko + 4);
        gload_lds16(pB0 + ko, (char*)sB[cur ^ 1] + wave * 1024);
        gload_lds16(pB1 + ko, (char*)sB[cur ^ 1] + wave * 1024 + 4096);
      } else {
        gload_lds16(bA0 + ko, (char*)sA[cur ^ 1] + wave * 1024);
        gload_lds16(bA1 + ko, (char*)sA[cur ^ 1] + wave * 1024 + 4096);
        gload_lds16(pB0 + ko, (char*)sB[cur ^ 1] + wave * 1024);
        gload_lds16(pB1 + ko, (char*)sB[cur ^ 1] + wave * 1024 + 4096);
      }
    }
    bf16x8 af[4], bfr[4];
    #pragma unroll
    for (int m = 0; m < 4; m++)
      af[m] = *reinterpret_cast<const bf16x8*>(&sA[cur][(wr * 64 + m * 16 + fr) * 32 + fkb]);
    #pragma unroll
    for (int n = 0; n < 4; n++)
      bfr[n] = *reinterpret_cast<const bf16x8*>(&sB[cur][(wc * 64 + n * 16 + fr) * 32 + fkb]);
    #pragma unroll
    for (int m = 0; m < 4; m++)
      #pragma unroll
      for (int n = 0; n < 4; n++)
        acc[m][n] = __builtin_amdgcn_mfma_f32_16x16x32_bf16(af[m], bfr[n], acc[m][n], 0, 0, 0);
    if (more) {
      if constexpr (AF32) {               // write-late: HBM latency hidden under MFMA
        *(u16x8*)&sA[cur ^ 1][aw0] = pack8(ra, rb);
        *(u16x8*)&sA[cur ^ 1][aw1] = pack8(rc, rd);
      }
    }
    __syncthreads();                      // vmcnt(0)+lgkmcnt(0) drain + barrier
    cur ^= 1;
  }

  // epilogue: C/D layout col=lane&15, row=(lane>>4)*4+reg (m89-verified)
  #pragma unroll
  for (int m = 0; m < 4; m++) {
    int lrow = wr * 64 + m * 16 + (lane >> 4) * 4;
    #pragma unroll
    for (int n = 0; n < 4; n++) {
      int col = nt * 128 + wc * 64 + n * 16 + (lane & 15);
      float bval = bi[col];
      #pragma unroll
      for (int r = 0; r < 4; r++) {
        int grow = mt * 128 + lrow + r;
        if (grow >= cnt) continue;
        float v = acc[m][n][r] + bval;
        if (EPI == 2) v = v / (1.f + __expf(-v));                        // silu
        if (EPI == 3) {                                                  // gelu tanh approx
          float z3 = v * v * v;
          v = 0.5f * v * (1.f + tanhf(0.7978845608028654f * (v + 0.044715f * z3)));
        }
        size_t cr = (size_t)(rowBase + grow) * ldc + colOff + col;
        if (EPI == 0) ((float*)Cv)[cr] = v;
        else          ((uint16_t*)Cv)[cr] = f2bf(v);
      }
    }
  }
}

// ---------------- gate-path fold helpers (all f32) ----------------
// Reassociated: G3 = Wv @ (Wo @ Wg)  — 33 MFLOP instead of 2.1 GFLOP
__global__ void bvwo_k(const float* __restrict__ bv, const float* __restrict__ Wo,
                       const float* __restrict__ bo, float* __restrict__ t1)
{
  int j = blockIdx.x * 256 + threadIdx.x;
  float s = 0.f;
  for (int k = 0; k < E_DIM; ++k) s = __builtin_fmaf(bv[k], Wo[(size_t)k * E_DIM + j], s);
  t1[j] = s + bo[j];
}

__global__ void g1_k(const float* __restrict__ Wo, const float* __restrict__ Wg,
                     float* __restrict__ g1)
{
  int idx = blockIdx.x * 256 + threadIdx.x;   // 8192 = 1024*8
  int k = idx >> 3, e = idx & 7;
  float s = 0.f;
  for (int m = 0; m < E_DIM; ++m) s = __builtin_fmaf(Wo[(size_t)k * E_DIM + m], Wg[m * 8 + e], s);
  g1[idx] = s;
}

__global__ void g2_k(const float* __restrict__ Wv, const float* __restrict__ g1,
                     float* __restrict__ G3)
{
  int idx = blockIdx.x * 256 + threadIdx.x;   // 8192
  int k = idx >> 3, e = idx & 7;
  float s = 0.f;
  for (int m = 0; m < E_DIM; ++m) s = __builtin_fmaf(Wv[(size_t)k * E_DIM + m], g1[m * 8 + e], s);
  G3[idx] = s;
}

__global__ void gbias_k(const float* __restrict__ t1, const float* __restrict__ Wg,
                        const float* __restrict__ bg, float* __restrict__ gb)
{
  int e = threadIdx.x;
  if (e < 8) {
    float s = 0.f;
    for (int k = 0; k < E_DIM; ++k) s = __builtin_fmaf(t1[k], Wg[k * 8 + e], s);
    gb[e] = s + bg[e];
  }
}

// ---------------- gate: logits -> softmax -> top2 -> counts ----------------
__global__ __launch_bounds__(256)
void gate_k(const float* __restrict__ text, const float* __restrict__ G3,
            const float* __restrict__ gb, float* __restrict__ gate_out,
            int* __restrict__ topIdx, float* __restrict__ topW,
            int* __restrict__ counts)
{
  __shared__ __align__(16) float sT[E_DIM];
  __shared__ float lg[8];
  int b = blockIdx.x, t = threadIdx.x;
  *(f32x4*)&sT[t * 4] = *(const f32x4*)&text[(size_t)b * E_DIM + t * 4];
  __syncthreads();
  int wave = t >> 6, lane = t & 63;
  #pragma unroll
  for (int ei = 0; ei < 2; ++ei) {
    int e = wave * 2 + ei;
    float s = 0.f;
    for (int k = lane; k < E_DIM; k += 64) s = __builtin_fmaf(sT[k], G3[k * 8 + e], s);
    #pragma unroll
    for (int off = 32; off; off >>= 1) s += __shfl_down(s, off);
    if (lane == 0) lg[e] = s + gb[e];
  }
  __syncthreads();
  if (t == 0) {
    float p[8];
    float mx = lg[0];
    for (int i = 1; i < 8; i++) mx = fmaxf(mx, lg[i]);
    float den = 0.f;
    for (int i = 0; i < 8; i++) { p[i] = __expf(lg[i] - mx); den += p[i]; }
    float inv = 1.f / den;
    for (int i = 0; i < 8; i++) { p[i] *= inv; gate_out[(size_t)b * 8 + i] = p[i]; }
    int i1 = 0;
    for (int i = 1; i < 8; i++) if (p[i] > p[i1]) i1 = i;       // ties -> lower index
    int i2 = (i1 == 0) ? 1 : 0;
    for (int i = 0; i < 8; i++) if (i != i1 && p[i] > p[i2]) i2 = i;
    float ex = __expf(p[i2] - p[i1]);                            // softmax over top-2 PROBS
    float w1 = 1.f / (1.f + ex), w2 = ex / (1.f + ex);
    topIdx[b * 2] = i1; topIdx[b * 2 + 1] = i2;
    topW[b * 2] = w1;  topW[b * 2 + 1] = w2;
    atomicAdd(&counts[i1], 1);
    atomicAdd(&counts[i2], 1);
  }
}

__global__ void imp_k(const float* __restrict__ gate_out, float* __restrict__ imp)
{
  int e = blockIdx.x, t = threadIdx.x;
  float s = 0.f;
  for (int b = t; b < B_TOK; b += 256) s += gate_out[(size_t)b * 8 + e];
  __shared__ float red[256];
  red[t] = s; __syncthreads();
  for (int off = 128; off; off >>= 1) { if (t < off) red[t] += red[t + off]; __syncthreads(); }
  if (t == 0) imp[e] = red[0];
}

__global__ void loss_k(const float* __restrict__ imp, float* __restrict__ out_loss)
{
  if (threadIdx.x == 0 && blockIdx.x == 0) {
    float m = 0.f;
    for (int e = 0; e < 8; e++) m += imp[e];
    m *= 0.125f;
    float v = 0.f;
    for (int e = 0; e < 8; e++) { float d = imp[e] - m; v += d * d; }
    v /= 7.f;                                  // ddof=1
    out_loss[0] = 0.01f * v / (m * m);
  }
}

__global__ void zero_k(int* counts, int* cursor)
{
  int t = threadIdx.x;
  if (t < 8) { counts[t] = 0; cursor[t] = 0; }
}

__global__ void scan_k(const int* __restrict__ counts, int* __restrict__ bases)
{
  if (threadIdx.x == 0) {
    int a = 0;
    for (int e = 0; e < 8; e++) { bases[e] = a; a += counts[e]; }
  }
}

__global__ void fill_k(const int* __restrict__ topIdx, int* __restrict__ cursor,
                       const int* __restrict__ bases, int* __restrict__ perm,
                       int* __restrict__ slotOf)
{
  int b = blockIdx.x * 256 + threadIdx.x;
  if (b < B_TOK) {
    #pragma unroll
    for (int j = 0; j < 2; j++) {
      int e = topIdx[b * 2 + j];
      int pos = atomicAdd(&cursor[e], 1);
      int slot = bases[e] + pos;
      perm[slot] = b;
      slotOf[b * 2 + j] = slot;
    }
  }
}

__global__ __launch_bounds__(256)
void combine_k(const float* __restrict__ Yg, const int* __restrict__ slotOf,
               const float* __restrict__ topW, float* __restrict__ y)
{
  int b = blockIdx.x, t = threadIdx.x;
  int s0 = slotOf[b * 2], s1 = slotOf[b * 2 + 1];
  float w0 = topW[b * 2], w1 = topW[b * 2 + 1];
  f32x4 a = *(const f32x4*)&Yg[(size_t)s0 * E_DIM + t * 4];
  f32x4 c = *(const f32x4*)&Yg[(size_t)s1 * E_DIM + t * 4];
  f32x4 r = a * w0 + c * w1;
  *(f32x4*)&y[(size_t)b * E_DIM + t * 4] = r;
}

// ---------------- host ----------------
extern "C" void kernel_launch(void* const* d_in, const int* in_sizes, int n_in,
                              void* d_out, int out_size, void* d_ws, size_t ws_size,
                              hipStream_t stream)
{
  (void)in_sizes; (void)n_in; (void)out_size;
  const float* src   = (const float*)d_in[0];
  const float* tgt   = (const float*)d_in[1];
  const float* bgr   = (const float*)d_in[2];
  const float* image = (const float*)d_in[3];
  const float* text  = (const float*)d_in[4];
  const float* W_enc = (const float*)d_in[5];
  const float* b_enc = (const float*)d_in[6];
  const float* W_img = (const float*)d_in[7];
  const float* b_img = (const float*)d_in[8];
  // d_in[9..12]: Wq,bq,Wk,bk — dead (softmax over length-1 key axis == 1)
  const float* Wv    = (const float*)d_in[13];
  const float* bv    = (const float*)d_in[14];
  const float* Wo    = (const float*)d_in[15];
  const float* bo    = (const float*)d_in[16];
  const float* Wg    = (const float*)d_in[17];
  const float* bgg   = (const float*)d_in[18];
  const float* W1    = (const float*)d_in[19];
  const float* b1    = (const float*)d_in[20];
  const float* W2    = (const float*)d_in[21];
  const float* b2    = (const float*)d_in[22];

  float* out_y    = (float*)d_out;
  float* out_gate = out_y + (size_t)B_TOK * E_DIM;
  float* out_loss = out_gate + (size_t)B_TOK * N_EXPC;

  char* p = (char*)d_ws;
  auto alloc = [&](size_t bytes) { char* r = p; p += (bytes + 255) & ~(size_t)255; return r; };
  uint16_t* WencT = (uint16_t*)alloc((size_t)OUT_DIM * IMGSZ * 2);
  uint16_t* WimgT = (uint16_t*)alloc((size_t)OUT_DIM * E_DIM * 2);
  uint16_t* W1T   = (uint16_t*)alloc((size_t)N_EXPC * HID * E_DIM * 2);
  uint16_t* W2T   = (uint16_t*)alloc((size_t)N_EXPC * E_DIM * HID * 2);
  float* g1c  = (float*)alloc((size_t)E_DIM * 8 * 4);
  float* G3   = (float*)alloc((size_t)E_DIM * 8 * 4);
  float* t1   = (float*)alloc(E_DIM * 4);
  float* gbv  = (float*)alloc(64 * 4);
  int*   topIdx = (int*)alloc(B_TOK * 2 * 4);
  float* topW   = (float*)alloc(B_TOK * 2 * 4);
  int*   slotOf = (int*)alloc(B_TOK * 2 * 4);
  int*   counts = (int*)alloc(64 * 4);
  int*   bases  = (int*)alloc(64 * 4);
  int*   cursor = (int*)alloc(64 * 4);
  int*   perm   = (int*)alloc(NSLOT * 4);
  uint16_t* xbf   = (uint16_t*)alloc((size_t)B_TOK * E_DIM * 2);
  uint16_t* Hbuf  = (uint16_t*)alloc((size_t)NSLOT * HID * 2);
  float*    Yg    = (float*)alloc((size_t)NSLOT * E_DIM * 4);
  if ((size_t)(p - (char*)d_ws) > ws_size) return;   // ws too small: fail visibly

  zero_k<<<1, 64, 0, stream>>>(counts, cursor);

  dim3 tb(32, 8);
  transpose_cvt<<<dim3(OUT_DIM / 32, IMGSZ / 32, 1), tb, 0, stream>>>(W_enc, WencT, IMGSZ, OUT_DIM);
  transpose_cvt<<<dim3(OUT_DIM / 32, E_DIM / 32, 1), tb, 0, stream>>>(W_img, WimgT, E_DIM, OUT_DIM);
  transpose_cvt<<<dim3(HID / 32, E_DIM / 32, 8), tb, 0, stream>>>(W1, W1T, E_DIM, HID);
  transpose_cvt<<<dim3(E_DIM / 32, HID / 32, 8), tb, 0, stream>>>(W2, W2T, HID, E_DIM);

  // gate fold (f32, precision-critical), reassociated to two skinny folds
  bvwo_k<<<4, 256, 0, stream>>>(bv, Wo, bo, t1);
  g1_k<<<32, 256, 0, stream>>>(Wo, Wg, g1c);
  g2_k<<<32, 256, 0, stream>>>(Wv, g1c, G3);
  gbias_k<<<1, 64, 0, stream>>>(t1, Wg, bgg, gbv);
  gate_k<<<B_TOK, 256, 0, stream>>>(text, G3, gbv, out_gate, topIdx, topW, counts);
  imp_k<<<8, 256, 0, stream>>>(out_gate, t1);
  loss_k<<<1, 64, 0, stream>>>(t1, out_loss);
  scan_k<<<1, 64, 0, stream>>>(counts, bases);
  fill_k<<<16, 256, 0, stream>>>(topIdx, cursor, bases, perm, slotOf);

  // visionFeatures x = [enc(s) | enc(t) | enc(bg) | silu(img@W_img+b)]  (bf16, f32-A fused)
  gemm128<1, false, false, true><<<dim3(B_TOK / 128, OUT_DIM / 128, 3), 256, 0, stream>>>(
      src, tgt, bgr, nullptr, IMGSZ, WencT, xbf, E_DIM, b_enc,
      B_TOK, OUT_DIM, IMGSZ, 0, OUT_DIM, nullptr, nullptr, nullptr, 0, 0);
  gemm128<2, false, false, true><<<dim3(B_TOK / 128, OUT_DIM / 128, 1), 256, 0, stream>>>(
      image, nullptr, nullptr, nullptr, E_DIM, WimgT, xbf, E_DIM, b_img,
      B_TOK, OUT_DIM, E_DIM, 3 * OUT_DIM, 0, nullptr, nullptr, nullptr, 0, 0);

  // sparse top-2 expert MLPs (double-buffered pipeline)
  gemm128<3, true, true, false><<<dim3(B_TOK / 128, HID / 128, 8), 256, 0, stream>>>(
      nullptr, nullptr, nullptr, xbf, E_DIM, W1T, Hbuf, HID, b1,
      B_TOK, HID, E_DIM, 0, 0, counts, bases, perm, (size_t)HID * E_DIM, HID);
  gemm128<0, true, false, false><<<dim3(B_TOK / 128, E_DIM / 128, 8), 256, 0, stream>>>(
      nullptr, nullptr, nullptr, Hbuf, HID, W2T, Yg, E_DIM, b2,
      B_TOK, E_DIM, HID, 0, 0, counts, bases, perm, (size_t)E_DIM * HID, E_DIM);

  combine_k<<<B_TOK, 256, 0, stream>>>(Yg, slotOf, topW, out_y);
}

// Round 3
// 950.669 us; speedup vs baseline: 1.6683x; 1.4777x over previous
//
#include <hip/hip_runtime.h>
#include <hip/hip_bf16.h>
#include <stdint.h>

typedef __bf16 bf16_t;
typedef bf16_t bf16x8 __attribute__((ext_vector_type(8)));
typedef float f32x4 __attribute__((ext_vector_type(4)));
typedef uint16_t u16x8 __attribute__((ext_vector_type(8)));

static constexpr int B_TOK  = 4096;
static constexpr int E_DIM  = 1024;
static constexpr int OUT_DIM= 256;
static constexpr int N_EXPC = 8;
static constexpr int HID    = 4096;
static constexpr int IMGSZ  = 4096;
static constexpr int NSLOT  = 2 * B_TOK;
static constexpr int MAXTILE= 72;          // sum ceil(cnt_e/128) <= 64+7

#define DEVI __device__ __forceinline__

DEVI int imin(int a, int b) { return a < b ? a : b; }

DEVI uint16_t f2bf(float f) {
  union { float f; uint32_t u; } v; v.f = f;
  uint32_t u = v.u;
  return (uint16_t)((u + 0x7FFFu + ((u >> 16) & 1u)) >> 16);
}

DEVI void gload_lds16(const void* g, void* l) {
  __builtin_amdgcn_global_load_lds((const __attribute__((address_space(1))) void*)g,
                                   (__attribute__((address_space(3))) void*)l, 16, 0, 0);
}

// ---------------- fused f32 -> bf16 convert for the 4 activation tensors ----------------
__global__ void cvt_all(const float* __restrict__ a0, const float* __restrict__ a1,
                        const float* __restrict__ a2, const float* __restrict__ a3,
                        uint16_t* __restrict__ o0, uint16_t* __restrict__ o1,
                        uint16_t* __restrict__ o2, uint16_t* __restrict__ o3)
{
  int y = blockIdx.y;
  const float* src = (y == 0) ? a0 : (y == 1) ? a1 : (y == 2) ? a2 : a3;
  uint16_t* dst = (y == 0) ? o0 : (y == 1) ? o1 : (y == 2) ? o2 : o3;
  int n8 = ((y < 3) ? (B_TOK * IMGSZ) : (B_TOK * E_DIM)) / 8;
  for (int i = blockIdx.x * 256 + threadIdx.x; i < n8; i += gridDim.x * 256) {
    f32x4 va = *(const f32x4*)(src + (size_t)i * 8);
    f32x4 vb = *(const f32x4*)(src + (size_t)i * 8 + 4);
    u16x8 o;
    o[0]=f2bf(va[0]); o[1]=f2bf(va[1]); o[2]=f2bf(va[2]); o[3]=f2bf(va[3]);
    o[4]=f2bf(vb[0]); o[5]=f2bf(vb[1]); o[6]=f2bf(vb[2]); o[7]=f2bf(vb[3]);
    *(u16x8*)(dst + (size_t)i * 8) = o;
  }
}

// ---------------- transpose + convert: in f32 [R][C] -> out bf16 [C][R], 64x64 tiles ----------------
__global__ __launch_bounds__(256)
void transpose64(const float* __restrict__ in, uint16_t* __restrict__ out, int R, int C)
{
  __shared__ float tile[64][65];
  size_t off = (size_t)blockIdx.z * (size_t)R * (size_t)C;
  int c0 = blockIdx.x * 64, r0 = blockIdx.y * 64;
  int t = threadIdx.x;
  #pragma unroll
  for (int i = 0; i < 16; ++i) {
    int rr = i * 4 + (t >> 6), cc = t & 63;
    tile[rr][cc] = in[off + (size_t)(r0 + rr) * C + c0 + cc];
  }
  __syncthreads();
  #pragma unroll
  for (int i = 0; i < 8; ++i) {
    int c = i * 8 + (t >> 5), j = t & 31;
    ushort2 w;
    w.x = f2bf(tile[2 * j][c]);
    w.y = f2bf(tile[2 * j + 1][c]);
    *(ushort2*)&out[off + (size_t)(c0 + c) * R + r0 + 2 * j] = w;
  }
}

// ---------------- unified bf16 MFMA GEMM: depth-2 counted-vmcnt pipeline ----------------
// C[M,N] = A[M,K] @ BT[N,K]^T (+bias, +activation)
// EPI: 0=f32, 1=bf16, 2=silu->bf16, 3=gelu(tanh)->bf16
// TILED: blockIdx.x indexes the compact expert-tile table meta[] = {nT, (e,rowBase,rows)*}
#define WAITV8 asm volatile("s_waitcnt vmcnt(8)" ::: "memory")
#define WAITV6 asm volatile("s_waitcnt vmcnt(6)" ::: "memory")
#define WAITV4 asm volatile("s_waitcnt vmcnt(4)" ::: "memory")
#define WAITV3 asm volatile("s_waitcnt vmcnt(3)" ::: "memory")
#define WAITV0 asm volatile("s_waitcnt vmcnt(0)" ::: "memory")

template<int BN, int EPI, bool GATHER, bool TILED>
__global__ __launch_bounds__(256, 3)
void gemm_p(const uint16_t* __restrict__ A0, const uint16_t* __restrict__ A1,
            const uint16_t* __restrict__ A2, int lda,
            const uint16_t* __restrict__ BT, void* __restrict__ Cv, int ldc,
            const float* __restrict__ bias, int K,
            int colBase, int colStride,
            const int* __restrict__ meta, const int* __restrict__ perm,
            size_t bStride, int biasStride)
{
  constexpr int HN = BN / 2, FN = BN / 32;
  int rowBase, rows, e, colOff;
  const uint16_t* A;
  if constexpr (TILED) {
    int i = blockIdx.x;
    if (i >= meta[0]) return;
    e = meta[1 + 3 * i]; rowBase = meta[2 + 3 * i]; rows = meta[3 + 3 * i];
    A = A0; colOff = 0;
  } else {
    int z = blockIdx.z;
    A = (z == 0) ? A0 : (z == 1) ? A1 : A2;
    rowBase = blockIdx.x * 128; rows = 128; e = 0;
    colOff = colBase + z * colStride;
  }
  int nt = blockIdx.y;
  const uint16_t* Bt = BT + (TILED ? (size_t)e * bStride : 0);
  const float* bi = bias + (TILED ? (size_t)e * (size_t)biasStride : 0);

  __shared__ __align__(16) uint16_t sA[3][128 * 32];
  __shared__ __align__(16) uint16_t sB[3][BN * 32];

  int t = threadIdx.x, wave = t >> 6, lane = t & 63;
  int wr = wave >> 1, wc = wave & 1;
  int r0 = t >> 2, r1 = r0 + 64;
  int sl = ((t & 3) ^ (r0 & 3)) * 8;          // T2-lite swizzled 16B slice (pre-swizzled source)
  int car0, car1;
  if constexpr (TILED) {
    int rr0 = imin(r0, rows - 1), rr1 = imin(r1, rows - 1);
    car0 = GATHER ? perm[rowBase + rr0] : rowBase + rr0;
    car1 = GATHER ? perm[rowBase + rr1] : rowBase + rr1;
  } else { car0 = rowBase + r0; car1 = rowBase + r1; }
  const uint16_t* gA0 = A + (size_t)car0 * lda + sl;
  const uint16_t* gA1 = A + (size_t)car1 * lda + sl;
  const uint16_t* gB0 = Bt + (size_t)(nt * BN + r0) * K + sl;
  const uint16_t* gB1 = Bt + (size_t)(nt * BN + (BN == 128 ? r1 : r0)) * K + sl;

  f32x4 acc[4][FN];
  #pragma unroll
  for (int m = 0; m < 4; m++)
    #pragma unroll
    for (int n = 0; n < FN; n++)
      acc[m][n] = f32x4{0.f, 0.f, 0.f, 0.f};

  int nk = K >> 5;
  char* laBase = (char*)&sA[0][0] + wave * 1024;
  char* lbBase = (char*)&sB[0][0] + wave * 1024;

  auto STAGE = [&](int kt, int c) {
    int ko = kt << 5;
    char* la = laBase + c * 8192;
    char* lb = lbBase + c * (BN == 128 ? 8192 : 4096);
    gload_lds16(gA0 + ko, la);
    gload_lds16(gA1 + ko, la + 4096);
    gload_lds16(gB0 + ko, lb);
    if constexpr (BN == 128) gload_lds16(gB1 + ko, lb + 4096);
  };

  STAGE(0, 0);
  STAGE(1, 1);

  int fr = lane & 15;
  int rdoff = ((lane >> 4) ^ (lane & 3)) * 16;   // read-side swizzle (byte offset in 64B row)
  int c0 = 0, c2 = 2;

  for (int kt = 0; kt < nk; ++kt) {
    if (kt + 2 < nk) {
      STAGE(kt + 2, c2);
      if constexpr (BN == 128) WAITV8; else WAITV6;   // tiles kt+1,kt+2 stay in flight
    } else if (kt + 1 < nk) {
      if constexpr (BN == 128) WAITV4; else WAITV3;
    } else {
      WAITV0;
    }
    __builtin_amdgcn_sched_barrier(0);
    __builtin_amdgcn_s_barrier();                   // raw barrier: no vmcnt(0) drain
    __builtin_amdgcn_sched_barrier(0);

    const char* bA = (const char*)&sA[0][0] + c0 * 8192;
    const char* bB = (const char*)&sB[0][0] + c0 * (BN == 128 ? 8192 : 4096);
    bf16x8 af[4], bfr[FN];
    #pragma unroll
    for (int m = 0; m < 4; m++)
      af[m] = *(const bf16x8*)(bA + (wr * 64 + m * 16 + fr) * 64 + rdoff);
    #pragma unroll
    for (int n = 0; n < FN; n++)
      bfr[n] = *(const bf16x8*)(bB + (wc * HN + n * 16 + fr) * 64 + rdoff);
    #pragma unroll
    for (int m = 0; m < 4; m++)
      #pragma unroll
      for (int n = 0; n < FN; n++)
        acc[m][n] = __builtin_amdgcn_mfma_f32_16x16x32_bf16(af[m], bfr[n], acc[m][n], 0, 0, 0);

    __builtin_amdgcn_sched_barrier(0);
    __builtin_amdgcn_s_barrier();                   // readers done before buffer reuse
    c0 = (c0 == 2) ? 0 : c0 + 1;
    c2 = (c2 == 2) ? 0 : c2 + 1;
  }

  // epilogue: C/D layout col=lane&15, row=(lane>>4)*4+reg (m89-verified)
  #pragma unroll
  for (int m = 0; m < 4; m++) {
    int lrow = wr * 64 + m * 16 + (lane >> 4) * 4;
    #pragma unroll
    for (int n = 0; n < FN; n++) {
      int col = nt * BN + wc * HN + n * 16 + (lane & 15);
      float bval = bi[col];
      #pragma unroll
      for (int r = 0; r < 4; r++) {
        int lr = lrow + r;
        if (TILED && lr >= rows) continue;
        float v = acc[m][n][r] + bval;
        if (EPI == 2) v = v / (1.f + __expf(-v));                        // silu
        if (EPI == 3) {                                                  // gelu tanh approx
          float z3 = v * v * v;
          v = 0.5f * v * (1.f + tanhf(0.7978845608028654f * (v + 0.044715f * z3)));
        }
        size_t cr = (size_t)(rowBase + lr) * ldc + colOff + col;
        if (EPI == 0) ((float*)Cv)[cr] = v;
        else          ((uint16_t*)Cv)[cr] = f2bf(v);
      }
    }
  }
}

// ---------------- gate-path fold helpers (all f32) ----------------
__global__ void bvwo_k(const float* __restrict__ bv, const float* __restrict__ Wo,
                       const float* __restrict__ bo, float* __restrict__ t1)
{
  int j = blockIdx.x * 256 + threadIdx.x;
  float s = 0.f;
  for (int k = 0; k < E_DIM; ++k) s = __builtin_fmaf(bv[k], Wo[(size_t)k * E_DIM + j], s);
  t1[j] = s + bo[j];
}

__global__ void g1_k(const float* __restrict__ Wo, const float* __restrict__ Wg,
                     float* __restrict__ g1)
{
  int idx = blockIdx.x * 256 + threadIdx.x;   // 8192
  int k = idx >> 3, e = idx & 7;
  float s = 0.f;
  for (int m = 0; m < E_DIM; ++m) s = __builtin_fmaf(Wo[(size_t)k * E_DIM + m], Wg[m * 8 + e], s);
  g1[idx] = s;
}

__global__ void g2_k(const float* __restrict__ Wv, const float* __restrict__ g1,
                     float* __restrict__ G3)
{
  int idx = blockIdx.x * 256 + threadIdx.x;   // 8192
  int k = idx >> 3, e = idx & 7;
  float s = 0.f;
  for (int m = 0; m < E_DIM; ++m) s = __builtin_fmaf(Wv[(size_t)k * E_DIM + m], g1[m * 8 + e], s);
  G3[idx] = s;
}

__global__ void gbias_k(const float* __restrict__ t1, const float* __restrict__ Wg,
                        const float* __restrict__ bg, float* __restrict__ gb)
{
  int e = threadIdx.x;
  if (e < 8) {
    float s = 0.f;
    for (int k = 0; k < E_DIM; ++k) s = __builtin_fmaf(t1[k], Wg[k * 8 + e], s);
    gb[e] = s + bg[e];
  }
}

// ---------------- gate: logits -> softmax -> top2 -> counts ----------------
__global__ __launch_bounds__(256)
void gate_k(const float* __restrict__ text, const float* __restrict__ G3,
            const float* __restrict__ gb, float* __restrict__ gate_out,
            int* __restrict__ topIdx, float* __restrict__ topW,
            int* __restrict__ counts)
{
  __shared__ __align__(16) float sT[E_DIM];
  __shared__ float lg[8];
  int b = blockIdx.x, t = threadIdx.x;
  *(f32x4*)&sT[t * 4] = *(const f32x4*)&text[(size_t)b * E_DIM + t * 4];
  __syncthreads();
  int wave = t >> 6, lane = t & 63;
  #pragma unroll
  for (int ei = 0; ei < 2; ++ei) {
    int e = wave * 2 + ei;
    float s = 0.f;
    for (int k = lane; k < E_DIM; k += 64) s = __builtin_fmaf(sT[k], G3[k * 8 + e], s);
    #pragma unroll
    for (int off = 32; off; off >>= 1) s += __shfl_down(s, off);
    if (lane == 0) lg[e] = s + gb[e];
  }
  __syncthreads();
  if (t == 0) {
    float p[8];
    float mx = lg[0];
    for (int i = 1; i < 8; i++) mx = fmaxf(mx, lg[i]);
    float den = 0.f;
    for (int i = 0; i < 8; i++) { p[i] = __expf(lg[i] - mx); den += p[i]; }
    float inv = 1.f / den;
    for (int i = 0; i < 8; i++) { p[i] *= inv; gate_out[(size_t)b * 8 + i] = p[i]; }
    int i1 = 0;
    for (int i = 1; i < 8; i++) if (p[i] > p[i1]) i1 = i;       // ties -> lower index
    int i2 = (i1 == 0) ? 1 : 0;
    for (int i = 0; i < 8; i++) if (i != i1 && p[i] > p[i2]) i2 = i;
    float ex = __expf(p[i2] - p[i1]);                            // softmax over top-2 probs
    float w1 = 1.f / (1.f + ex), w2 = ex / (1.f + ex);
    topIdx[b * 2] = i1; topIdx[b * 2 + 1] = i2;
    topW[b * 2] = w1;  topW[b * 2 + 1] = w2;
    atomicAdd(&counts[i1], 1);
    atomicAdd(&counts[i2], 1);
  }
}

__global__ void imp_k(const float* __restrict__ gate_out, float* __restrict__ imp)
{
  int e = blockIdx.x, t = threadIdx.x;
  float s = 0.f;
  for (int b = t; b < B_TOK; b += 256) s += gate_out[(size_t)b * 8 + e];
  __shared__ float red[256];
  red[t] = s; __syncthreads();
  for (int off = 128; off; off >>= 1) { if (t < off) red[t] += red[t + off]; __syncthreads(); }
  if (t == 0) imp[e] = red[0];
}

__global__ void loss_k(const float* __restrict__ imp, float* __restrict__ out_loss)
{
  if (threadIdx.x == 0 && blockIdx.x == 0) {
    float m = 0.f;
    for (int e = 0; e < 8; e++) m += imp[e];
    m *= 0.125f;
    float v = 0.f;
    for (int e = 0; e < 8; e++) { float d = imp[e] - m; v += d * d; }
    v /= 7.f;                                  // ddof=1
    out_loss[0] = 0.01f * v / (m * m);
  }
}

__global__ void zero_k(int* counts, int* cursor)
{
  int t = threadIdx.x;
  if (t < 8) { counts[t] = 0; cursor[t] = 0; }
}

// prefix-scan + compact 128-row tile table: meta = {nT, (e, rowBase, rows)*}
__global__ void scan_k(const int* __restrict__ counts, int* __restrict__ bases,
                       int* __restrict__ meta)
{
  if (threadIdx.x == 0) {
    int a = 0, nt = 0;
    for (int e = 0; e < 8; e++) {
      bases[e] = a;
      int c = counts[e];
      for (int j = 0; j < c; j += 128) {
        meta[1 + 3 * nt] = e;
        meta[2 + 3 * nt] = a + j;
        meta[3 + 3 * nt] = (c - j < 128) ? (c - j) : 128;
        nt++;
      }
      a += c;
    }
    meta[0] = nt;
  }
}

__global__ void fill_k(const int* __restrict__ topIdx, int* __restrict__ cursor,
                       const int* __restrict__ bases, int* __restrict__ perm,
                       int* __restrict__ slotOf)
{
  int b = blockIdx.x * 256 + threadIdx.x;
  if (b < B_TOK) {
    #pragma unroll
    for (int j = 0; j < 2; j++) {
      int e = topIdx[b * 2 + j];
      int pos = atomicAdd(&cursor[e], 1);
      int slot = bases[e] + pos;
      perm[slot] = b;
      slotOf[b * 2 + j] = slot;
    }
  }
}

__global__ __launch_bounds__(256)
void combine_k(const float* __restrict__ Yg, const int* __restrict__ slotOf,
               const float* __restrict__ topW, float* __restrict__ y)
{
  int b = blockIdx.x, t = threadIdx.x;
  int s0 = slotOf[b * 2], s1 = slotOf[b * 2 + 1];
  float w0 = topW[b * 2], w1 = topW[b * 2 + 1];
  f32x4 a = *(const f32x4*)&Yg[(size_t)s0 * E_DIM + t * 4];
  f32x4 c = *(const f32x4*)&Yg[(size_t)s1 * E_DIM + t * 4];
  f32x4 r = a * w0 + c * w1;
  *(f32x4*)&y[(size_t)b * E_DIM + t * 4] = r;
}

// ---------------- host ----------------
extern "C" void kernel_launch(void* const* d_in, const int* in_sizes, int n_in,
                              void* d_out, int out_size, void* d_ws, size_t ws_size,
                              hipStream_t stream)
{
  (void)in_sizes; (void)n_in; (void)out_size;
  const float* src   = (const float*)d_in[0];
  const float* tgt   = (const float*)d_in[1];
  const float* bgr   = (const float*)d_in[2];
  const float* image = (const float*)d_in[3];
  const float* text  = (const float*)d_in[4];
  const float* W_enc = (const float*)d_in[5];
  const float* b_enc = (const float*)d_in[6];
  const float* W_img = (const float*)d_in[7];
  const float* b_img = (const float*)d_in[8];
  // d_in[9..12]: Wq,bq,Wk,bk — dead (softmax over length-1 key axis == 1)
  const float* Wv    = (const float*)d_in[13];
  const float* bv    = (const float*)d_in[14];
  const float* Wo    = (const float*)d_in[15];
  const float* bo    = (const float*)d_in[16];
  const float* Wg    = (const float*)d_in[17];
  const float* bgg   = (const float*)d_in[18];
  const float* W1    = (const float*)d_in[19];
  const float* b1    = (const float*)d_in[20];
  const float* W2    = (const float*)d_in[21];
  const float* b2    = (const float*)d_in[22];

  float* out_y    = (float*)d_out;
  float* out_gate = out_y + (size_t)B_TOK * E_DIM;
  float* out_loss = out_gate + (size_t)B_TOK * N_EXPC;

  char* p = (char*)d_ws;
  auto alloc = [&](size_t bytes) { char* r = p; p += (bytes + 255) & ~(size_t)255; return r; };
  uint16_t* WencT = (uint16_t*)alloc((size_t)OUT_DIM * IMGSZ * 2);
  uint16_t* WimgT = (uint16_t*)alloc((size_t)OUT_DIM * E_DIM * 2);
  uint16_t* W1T   = (uint16_t*)alloc((size_t)N_EXPC * HID * E_DIM * 2);
  uint16_t* W2T   = (uint16_t*)alloc((size_t)N_EXPC * E_DIM * HID * 2);
  float* g1c  = (float*)alloc((size_t)E_DIM * 8 * 4);
  float* G3   = (float*)alloc((size_t)E_DIM * 8 * 4);
  float* t1   = (float*)alloc(E_DIM * 4);
  float* gbv  = (float*)alloc(64 * 4);
  int*   topIdx = (int*)alloc(B_TOK * 2 * 4);
  float* topW   = (float*)alloc(B_TOK * 2 * 4);
  int*   slotOf = (int*)alloc(B_TOK * 2 * 4);
  int*   counts = (int*)alloc(64 * 4);
  int*   bases  = (int*)alloc(64 * 4);
  int*   cursor = (int*)alloc(64 * 4);
  int*   meta   = (int*)alloc((1 + 3 * MAXTILE) * 4 + 64);
  int*   perm   = (int*)alloc(NSLOT * 4);
  uint16_t* xbf   = (uint16_t*)alloc((size_t)B_TOK * E_DIM * 2);
  uint16_t* imgBf = (uint16_t*)alloc((size_t)B_TOK * E_DIM * 2);
  float*    Yg    = (float*)alloc((size_t)NSLOT * E_DIM * 4);
  // big region: 3 bf16 enc inputs (96 MB), later reused as Hbuf (64 MB)
  uint16_t* bigR  = (uint16_t*)alloc((size_t)3 * B_TOK * IMGSZ * 2);
  uint16_t* srcBf = bigR;
  uint16_t* tgtBf = bigR + (size_t)B_TOK * IMGSZ;
  uint16_t* bgrBf = bigR + (size_t)2 * B_TOK * IMGSZ;
  uint16_t* Hbuf  = bigR;                       // alias: live only after enc GEMMs finish
  if ((size_t)(p - (char*)d_ws) > ws_size) return;   // ws too small: fail visibly

  zero_k<<<1, 64, 0, stream>>>(counts, cursor);

  // activations f32 -> bf16 (one fused pass)
  cvt_all<<<dim3(1024, 4), 256, 0, stream>>>(src, tgt, bgr, image, srcBf, tgtBf, bgrBf, imgBf);

  // weight transposes (f32 [R][C] -> bf16 [C][R]) with vectorized ushort2 writes
  transpose64<<<dim3(OUT_DIM / 64, IMGSZ / 64, 1), 256, 0, stream>>>(W_enc, WencT, IMGSZ, OUT_DIM);
  transpose64<<<dim3(OUT_DIM / 64, E_DIM / 64, 1), 256, 0, stream>>>(W_img, WimgT, E_DIM, OUT_DIM);
  transpose64<<<dim3(HID / 64, E_DIM / 64, 8), 256, 0, stream>>>(W1, W1T, E_DIM, HID);
  transpose64<<<dim3(E_DIM / 64, HID / 64, 8), 256, 0, stream>>>(W2, W2T, HID, E_DIM);

  // gate fold (f32, precision-critical): logits = text@(Wv@(Wo@Wg)) + ((bv@Wo+bo)@Wg + bg)
  bvwo_k<<<4, 256, 0, stream>>>(bv, Wo, bo, t1);
  g1_k<<<32, 256, 0, stream>>>(Wo, Wg, g1c);
  g2_k<<<32, 256, 0, stream>>>(Wv, g1c, G3);
  gbias_k<<<1, 64, 0, stream>>>(t1, Wg, bgg, gbv);
  gate_k<<<B_TOK, 256, 0, stream>>>(text, G3, gbv, out_gate, topIdx, topW, counts);
  imp_k<<<8, 256, 0, stream>>>(out_gate, t1);
  loss_k<<<1, 64, 0, stream>>>(t1, out_loss);
  scan_k<<<1, 64, 0, stream>>>(counts, bases, meta);
  fill_k<<<16, 256, 0, stream>>>(topIdx, cursor, bases, perm, slotOf);

  // visionFeatures x = [enc(s)|enc(t)|enc(bg)|silu(img@W_img+b)]  (bf16 GEMMs, BN=64)
  gemm_p<64, 1, false, false><<<dim3(B_TOK / 128, OUT_DIM / 64, 3), 256, 0, stream>>>(
      srcBf, tgtBf, bgrBf, IMGSZ, WencT, xbf, E_DIM, b_enc,
      IMGSZ, 0, OUT_DIM, nullptr, nullptr, 0, 0);
  gemm_p<64, 2, false, false><<<dim3(B_TOK / 128, OUT_DIM / 64, 1), 256, 0, stream>>>(
      imgBf, nullptr, nullptr, E_DIM, WimgT, xbf, E_DIM, b_img,
      E_DIM, 3 * OUT_DIM, 0, nullptr, nullptr, 0, 0);

  // sparse top-2 expert MLPs, compact tile grid (meta), depth-2 pipeline
  gemm_p<128, 3, true, true><<<dim3(MAXTILE - 1, HID / 128, 1), 256, 0, stream>>>(
      xbf, nullptr, nullptr, E_DIM, W1T, Hbuf, HID, b1,
      E_DIM, 0, 0, meta, perm, (size_t)HID * E_DIM, HID);
  gemm_p<128, 0, false, true><<<dim3(MAXTILE - 1, E_DIM / 128, 1), 256, 0, stream>>>(
      Hbuf, nullptr, nullptr, HID, W2T, Yg, E_DIM, b2,
      HID, 0, 0, meta, perm, (size_t)E_DIM * HID, E_DIM);

  combine_k<<<B_TOK, 256, 0, stream>>>(Yg, slotOf, topW, out_y);
}

// Round 4
// 833.935 us; speedup vs baseline: 1.9018x; 1.1400x over previous
//
#include <hip/hip_runtime.h>
#include <hip/hip_bf16.h>
#include <stdint.h>

typedef __bf16 bf16_t;
typedef bf16_t bf16x8 __attribute__((ext_vector_type(8)));
typedef float f32x4 __attribute__((ext_vector_type(4)));

static constexpr int B_TOK  = 4096;
static constexpr int E_DIM  = 1024;
static constexpr int OUT_DIM= 256;
static constexpr int N_EXPC = 8;
static constexpr int HID    = 4096;
static constexpr int IMGSZ  = 4096;
static constexpr int NSLOT  = 2 * B_TOK;
static constexpr int NTIL   = 71;          // max 128-row tiles: 64 + 7 remainder tiles

#define DEVI __device__ __forceinline__

DEVI int imin(int a, int b) { return a < b ? a : b; }

DEVI uint16_t f2bf(float f) {
  union { float f; uint32_t u; } v; v.f = f;
  uint32_t u = v.u;
  return (uint16_t)((u + 0x7FFFu + ((u >> 16) & 1u)) >> 16);
}

DEVI void gload_lds16(const void* g, void* l) {
  __builtin_amdgcn_global_load_lds((const __attribute__((address_space(1))) void*)g,
                                   (__attribute__((address_space(3))) void*)l, 16, 0, 0);
}

template<int N> DEVI void waitv() {
  if constexpr (N == 0)       asm volatile("s_waitcnt vmcnt(0)" ::: "memory");
  else if constexpr (N == 3)  asm volatile("s_waitcnt vmcnt(3)" ::: "memory");
  else if constexpr (N == 4)  asm volatile("s_waitcnt vmcnt(4)" ::: "memory");
  else if constexpr (N == 5)  asm volatile("s_waitcnt vmcnt(5)" ::: "memory");
  else if constexpr (N == 6)  asm volatile("s_waitcnt vmcnt(6)" ::: "memory");
  else if constexpr (N == 8)  asm volatile("s_waitcnt vmcnt(8)" ::: "memory");
  else if constexpr (N == 10) asm volatile("s_waitcnt vmcnt(10)" ::: "memory");
}

// ---------------- transpose + convert: in f32 [R][C] -> out bf16 [C][R], 64x64 tiles ----------------
__global__ __launch_bounds__(256)
void transpose64(const float* __restrict__ in, uint16_t* __restrict__ out, int R, int C)
{
  __shared__ float tile[64][65];
  size_t off = (size_t)blockIdx.z * (size_t)R * (size_t)C;
  int c0 = blockIdx.x * 64, r0 = blockIdx.y * 64;
  int t = threadIdx.x;
  #pragma unroll
  for (int i = 0; i < 16; ++i) {
    int rr = i * 4 + (t >> 6), cc = t & 63;
    tile[rr][cc] = in[off + (size_t)(r0 + rr) * C + c0 + cc];
  }
  __syncthreads();
  #pragma unroll
  for (int i = 0; i < 8; ++i) {
    int c = i * 8 + (t >> 5), j = t & 31;
    ushort2 w;
    w.x = f2bf(tile[2 * j][c]);
    w.y = f2bf(tile[2 * j + 1][c]);
    *(ushort2*)&out[off + (size_t)(c0 + c) * R + r0 + 2 * j] = w;
  }
}

// ---------------- unified MFMA GEMM: depth-2 counted-vmcnt pipeline ----------------
// C[M,N] = A[M,K] @ BT[N,K]^T (+bias, +activation)
// EPI: 0=f32, 1=bf16, 2=silu->bf16, 3=gelu(tanh)->bf16
// TILED: 1D grid over compact expert tiles with supertile raster + XCD swizzle
// AF32: A is f32, staged raw into LDS (8-granule XOR swizzle), cvt->bf16 on read
template<int BN, int EPI, bool GATHER, bool TILED, bool AF32, int NT>
__global__ __launch_bounds__(256, AF32 ? 2 : 3)
void gemm_p(const float* __restrict__ F0, const float* __restrict__ F1,
            const float* __restrict__ F2, const uint16_t* __restrict__ Ab,
            int lda,
            const uint16_t* __restrict__ BT, void* __restrict__ Cv, int ldc,
            const float* __restrict__ bias, int K,
            int colBase, int colStride,
            const int* __restrict__ meta, const int* __restrict__ perm,
            size_t bStride, int biasStride)
{
  constexpr int HN = BN / 2, FN = BN / 32;
  constexpr int OPS = AF32 ? 5 : (BN == 128 ? 4 : 3);
  int rowBase, rows, e, colOff, nt;
  if constexpr (TILED) {
    constexpr int TOTAL = NTIL * NT, Q = TOTAL / 8, FULLB = 64 * NT;
    int bid = blockIdx.x;
    int wg = (bid & 7) * Q + (bid >> 3);            // bijective XCD swizzle (m204)
    int mtile;
    if (wg < FULLB) { int rem = wg % (8 * NT); mtile = (wg / (8 * NT)) * 8 + (rem & 7); nt = rem >> 3; }
    else            { int rem = wg - FULLB;    mtile = 64 + rem % 7;                    nt = rem / 7; }
    if (mtile >= meta[0]) return;
    e = meta[1 + 3 * mtile]; rowBase = meta[2 + 3 * mtile]; rows = meta[3 + 3 * mtile];
    colOff = 0;
  } else {
    e = 0; rowBase = blockIdx.x * 128; rows = 128;
    nt = blockIdx.y;
    colOff = colBase + blockIdx.z * colStride;
  }
  const uint16_t* Bt = BT + (TILED ? (size_t)e * bStride : 0);
  const float* bi = bias + (TILED ? (size_t)e * (size_t)biasStride : 0);

  constexpr int ABUF = AF32 ? 16384 : 8192;
  constexpr int BBUF = (BN == 128) ? 8192 : 4096;
  __shared__ __align__(16) char sAraw[3 * ABUF];
  __shared__ __align__(16) char sBraw[3 * BBUF];

  int t = threadIdx.x, wave = t >> 6, lane = t & 63;
  int wr = wave >> 1, wc = wave & 1;

  // B staging (bf16): 16B slices, granule XOR (t&3)^(row&3)
  int rB = t >> 2;
  int slB = ((t & 3) ^ (rB & 3)) * 8;
  const uint16_t* gB0 = Bt + (size_t)(nt * BN + rB) * K + slB;
  const uint16_t* gB1 = Bt + (size_t)(nt * BN + rB + 64) * K + slB;   // BN==128 only

  // A staging
  const uint16_t *gA0 = nullptr, *gA1 = nullptr;
  const float* gF[4] = {nullptr, nullptr, nullptr, nullptr};
  if constexpr (AF32) {
    const float* Af = (blockIdx.z == 0) ? F0 : (blockIdx.z == 1) ? F1 : F2;
    int g = (t & 7) ^ ((t >> 3) & 7);           // pre-swizzled source granule
    #pragma unroll
    for (int i = 0; i < 4; ++i) {
      int r = i * 32 + (t >> 3);
      gF[i] = Af + (size_t)(rowBase + r) * lda + g * 4;
    }
  } else {
    int r0 = t >> 2, r1 = r0 + 64;
    int sl = ((t & 3) ^ (r0 & 3)) * 8;
    int car0, car1;
    if constexpr (TILED) {
      int rr0 = imin(r0, rows - 1), rr1 = imin(r1, rows - 1);
      car0 = GATHER ? perm[rowBase + rr0] : rowBase + rr0;
      car1 = GATHER ? perm[rowBase + rr1] : rowBase + rr1;
    } else { car0 = rowBase + r0; car1 = rowBase + r1; }
    gA0 = Ab + (size_t)car0 * lda + sl;
    gA1 = Ab + (size_t)car1 * lda + sl;
  }

  char* laW = sAraw + wave * 1024;
  char* lbW = sBraw + wave * 1024;
  auto STAGE = [&](int kt, int c) {
    int ko = kt << 5;                              // 32 elements per K-step
    char* la = laW + c * ABUF;
    char* lb = lbW + c * BBUF;
    if constexpr (AF32) {
      #pragma unroll
      for (int i = 0; i < 4; ++i)
        gload_lds16(gF[i] + ko, la + i * 4096);
    } else {
      gload_lds16(gA0 + ko, la);
      gload_lds16(gA1 + ko, la + 4096);
    }
    gload_lds16(gB0 + ko, lb);
    if constexpr (BN == 128) gload_lds16(gB1 + ko, lb + 4096);
  };

  f32x4 acc[4][FN];
  #pragma unroll
  for (int m = 0; m < 4; m++)
    #pragma unroll
    for (int n = 0; n < FN; n++)
      acc[m][n] = f32x4{0.f, 0.f, 0.f, 0.f};

  STAGE(0, 0);
  STAGE(1, 1);

  int fr = lane & 15;
  int rdoff = ((lane >> 4) ^ (lane & 3)) * 16;     // bf16 read-side swizzle
  int c0 = 0, c2 = 2;
  int nk = K >> 5;

  for (int kt = 0; kt < nk; ++kt) {
    if (kt + 2 < nk) { STAGE(kt + 2, c2); waitv<2 * OPS>(); }   // 2 K-tiles stay in flight
    else if (kt + 1 < nk) waitv<OPS>();
    else waitv<0>();
    __builtin_amdgcn_sched_barrier(0);
    __builtin_amdgcn_s_barrier();                  // raw barrier: no vmcnt(0) drain
    __builtin_amdgcn_sched_barrier(0);

    const char* bA = sAraw + c0 * ABUF;
    const char* bB = sBraw + c0 * BBUF;
    bf16x8 af[4], bfr[FN];
    #pragma unroll
    for (int m = 0; m < 4; m++) {
      int rr = wr * 64 + m * 16 + fr;
      if constexpr (AF32) {
        int slot0 = ((lane >> 4) * 2) ^ (rr & 7);
        f32x4 lo = *(const f32x4*)(bA + rr * 128 + slot0 * 16);
        f32x4 hi = *(const f32x4*)(bA + rr * 128 + (slot0 ^ 1) * 16);
        bf16x8 v;
        v[0] = (bf16_t)lo[0]; v[1] = (bf16_t)lo[1]; v[2] = (bf16_t)lo[2]; v[3] = (bf16_t)lo[3];
        v[4] = (bf16_t)hi[0]; v[5] = (bf16_t)hi[1]; v[6] = (bf16_t)hi[2]; v[7] = (bf16_t)hi[3];
        af[m] = v;
      } else {
        af[m] = *(const bf16x8*)(bA + rr * 64 + rdoff);
      }
    }
    #pragma unroll
    for (int n = 0; n < FN; n++)
      bfr[n] = *(const bf16x8*)(bB + (wc * HN + n * 16 + fr) * 64 + rdoff);
    #pragma unroll
    for (int m = 0; m < 4; m++)
      #pragma unroll
      for (int n = 0; n < FN; n++)
        acc[m][n] = __builtin_amdgcn_mfma_f32_16x16x32_bf16(af[m], bfr[n], acc[m][n], 0, 0, 0);

    __builtin_amdgcn_sched_barrier(0);
    __builtin_amdgcn_s_barrier();                  // readers done before buffer reuse
    c0 = (c0 == 2) ? 0 : c0 + 1;
    c2 = (c2 == 2) ? 0 : c2 + 1;
  }

  // epilogue: C/D layout col=lane&15, row=(lane>>4)*4+reg (m89-verified)
  #pragma unroll
  for (int m = 0; m < 4; m++) {
    int lrow = wr * 64 + m * 16 + (lane >> 4) * 4;
    #pragma unroll
    for (int n = 0; n < FN; n++) {
      int col = nt * BN + wc * HN + n * 16 + (lane & 15);
      float bval = bi[col];
      #pragma unroll
      for (int r = 0; r < 4; r++) {
        int lr = lrow + r;
        if (TILED && lr >= rows) continue;
        float v = acc[m][n][r] + bval;
        if (EPI == 2) v = v / (1.f + __expf(-v));                        // silu
        if (EPI == 3) {                                                  // gelu tanh approx
          float z3 = v * v * v;
          v = 0.5f * v * (1.f + tanhf(0.7978845608028654f * (v + 0.044715f * z3)));
        }
        size_t cr = (size_t)(rowBase + lr) * ldc + colOff + col;
        if (EPI == 0) ((float*)Cv)[cr] = v;
        else          ((uint16_t*)Cv)[cr] = f2bf(v);
      }
    }
  }
}

// ---------------- gate-path fold helpers (all f32) ----------------
__global__ void bvwo_k(const float* __restrict__ bv, const float* __restrict__ Wo,
                       const float* __restrict__ bo, float* __restrict__ t1)
{
  int j = blockIdx.x * 256 + threadIdx.x;
  float s = 0.f;
  for (int k = 0; k < E_DIM; ++k) s = __builtin_fmaf(bv[k], Wo[(size_t)k * E_DIM + j], s);
  t1[j] = s + bo[j];
}

__global__ void g1_k(const float* __restrict__ Wo, const float* __restrict__ Wg,
                     float* __restrict__ g1)
{
  int idx = blockIdx.x * 256 + threadIdx.x;   // 8192
  int k = idx >> 3, e = idx & 7;
  float s = 0.f;
  for (int m = 0; m < E_DIM; ++m) s = __builtin_fmaf(Wo[(size_t)k * E_DIM + m], Wg[m * 8 + e], s);
  g1[idx] = s;
}

__global__ void g2_k(const float* __restrict__ Wv, const float* __restrict__ g1,
                     float* __restrict__ G3)
{
  int idx = blockIdx.x * 256 + threadIdx.x;   // 8192
  int k = idx >> 3, e = idx & 7;
  float s = 0.f;
  for (int m = 0; m < E_DIM; ++m) s = __builtin_fmaf(Wv[(size_t)k * E_DIM + m], g1[m * 8 + e], s);
  G3[idx] = s;
}

__global__ void gbias_k(const float* __restrict__ t1, const float* __restrict__ Wg,
                        const float* __restrict__ bg, float* __restrict__ gb)
{
  int e = threadIdx.x;
  if (e < 8) {
    float s = 0.f;
    for (int k = 0; k < E_DIM; ++k) s = __builtin_fmaf(t1[k], Wg[k * 8 + e], s);
    gb[e] = s + bg[e];
  }
}

// ---------------- gate: logits -> softmax -> top2 -> counts ----------------
__global__ __launch_bounds__(256)
void gate_k(const float* __restrict__ text, const float* __restrict__ G3,
            const float* __restrict__ gb, float* __restrict__ gate_out,
            int* __restrict__ topIdx, float* __restrict__ topW,
            int* __restrict__ counts)
{
  __shared__ __align__(16) float sT[E_DIM];
  __shared__ float lg[8];
  int b = blockIdx.x, t = threadIdx.x;
  *(f32x4*)&sT[t * 4] = *(const f32x4*)&text[(size_t)b * E_DIM + t * 4];
  __syncthreads();
  int wave = t >> 6, lane = t & 63;
  #pragma unroll
  for (int ei = 0; ei < 2; ++ei) {
    int e = wave * 2 + ei;
    float s = 0.f;
    for (int k = lane; k < E_DIM; k += 64) s = __builtin_fmaf(sT[k], G3[k * 8 + e], s);
    #pragma unroll
    for (int off = 32; off; off >>= 1) s += __shfl_down(s, off);
    if (lane == 0) lg[e] = s + gb[e];
  }
  __syncthreads();
  if (t == 0) {
    float p[8];
    float mx = lg[0];
    for (int i = 1; i < 8; i++) mx = fmaxf(mx, lg[i]);
    float den = 0.f;
    for (int i = 0; i < 8; i++) { p[i] = __expf(lg[i] - mx); den += p[i]; }
    float inv = 1.f / den;
    for (int i = 0; i < 8; i++) { p[i] *= inv; gate_out[(size_t)b * 8 + i] = p[i]; }
    int i1 = 0;
    for (int i = 1; i < 8; i++) if (p[i] > p[i1]) i1 = i;       // ties -> lower index
    int i2 = (i1 == 0) ? 1 : 0;
    for (int i = 0; i < 8; i++) if (i != i1 && p[i] > p[i2]) i2 = i;
    float ex = __expf(p[i2] - p[i1]);                            // softmax over top-2 probs
    float w1 = 1.f / (1.f + ex), w2 = ex / (1.f + ex);
    topIdx[b * 2] = i1; topIdx[b * 2 + 1] = i2;
    topW[b * 2] = w1;  topW[b * 2 + 1] = w2;
    atomicAdd(&counts[i1], 1);
    atomicAdd(&counts[i2], 1);
  }
}

__global__ void imp_k(const float* __restrict__ gate_out, float* __restrict__ imp)
{
  int e = blockIdx.x, t = threadIdx.x;
  float s = 0.f;
  for (int b = t; b < B_TOK; b += 256) s += gate_out[(size_t)b * 8 + e];
  __shared__ float red[256];
  red[t] = s; __syncthreads();
  for (int off = 128; off; off >>= 1) { if (t < off) red[t] += red[t + off]; __syncthreads(); }
  if (t == 0) imp[e] = red[0];
}

__global__ void loss_k(const float* __restrict__ imp, float* __restrict__ out_loss)
{
  if (threadIdx.x == 0 && blockIdx.x == 0) {
    float m = 0.f;
    for (int e = 0; e < 8; e++) m += imp[e];
    m *= 0.125f;
    float v = 0.f;
    for (int e = 0; e < 8; e++) { float d = imp[e] - m; v += d * d; }
    v /= 7.f;                                  // ddof=1
    out_loss[0] = 0.01f * v / (m * m);
  }
}

__global__ void zero_k(int* counts, int* cursor)
{
  int t = threadIdx.x;
  if (t < 8) { counts[t] = 0; cursor[t] = 0; }
}

// prefix-scan + compact 128-row tile table: meta = {nT, (e, rowBase, rows)*}
__global__ void scan_k(const int* __restrict__ counts, int* __restrict__ bases,
                       int* __restrict__ meta)
{
  if (threadIdx.x == 0) {
    int a = 0, nt = 0;
    for (int e = 0; e < 8; e++) {
      bases[e] = a;
      int c = counts[e];
      for (int j = 0; j < c; j += 128) {
        meta[1 + 3 * nt] = e;
        meta[2 + 3 * nt] = a + j;
        meta[3 + 3 * nt] = (c - j < 128) ? (c - j) : 128;
        nt++;
      }
      a += c;
    }
    meta[0] = nt;
  }
}

__global__ void fill_k(const int* __restrict__ topIdx, int* __restrict__ cursor,
                       const int* __restrict__ bases, int* __restrict__ perm,
                       int* __restrict__ slotOf)
{
  int b = blockIdx.x * 256 + threadIdx.x;
  if (b < B_TOK) {
    #pragma unroll
    for (int j = 0; j < 2; j++) {
      int e = topIdx[b * 2 + j];
      int pos = atomicAdd(&cursor[e], 1);
      int slot = bases[e] + pos;
      perm[slot] = b;
      slotOf[b * 2 + j] = slot;
    }
  }
}

__global__ __launch_bounds__(256)
void combine_k(const float* __restrict__ Yg, const int* __restrict__ slotOf,
               const float* __restrict__ topW, float* __restrict__ y)
{
  int b = blockIdx.x, t = threadIdx.x;
  int s0 = slotOf[b * 2], s1 = slotOf[b * 2 + 1];
  float w0 = topW[b * 2], w1 = topW[b * 2 + 1];
  f32x4 a = *(const f32x4*)&Yg[(size_t)s0 * E_DIM + t * 4];
  f32x4 c = *(const f32x4*)&Yg[(size_t)s1 * E_DIM + t * 4];
  f32x4 r = a * w0 + c * w1;
  *(f32x4*)&y[(size_t)b * E_DIM + t * 4] = r;
}

// ---------------- host ----------------
extern "C" void kernel_launch(void* const* d_in, const int* in_sizes, int n_in,
                              void* d_out, int out_size, void* d_ws, size_t ws_size,
                              hipStream_t stream)
{
  (void)in_sizes; (void)n_in; (void)out_size;
  const float* src   = (const float*)d_in[0];
  const float* tgt   = (const float*)d_in[1];
  const float* bgr   = (const float*)d_in[2];
  const float* image = (const float*)d_in[3];
  const float* text  = (const float*)d_in[4];
  const float* W_enc = (const float*)d_in[5];
  const float* b_enc = (const float*)d_in[6];
  const float* W_img = (const float*)d_in[7];
  const float* b_img = (const float*)d_in[8];
  // d_in[9..12]: Wq,bq,Wk,bk — dead (softmax over length-1 key axis == 1)
  const float* Wv    = (const float*)d_in[13];
  const float* bv    = (const float*)d_in[14];
  const float* Wo    = (const float*)d_in[15];
  const float* bo    = (const float*)d_in[16];
  const float* Wg    = (const float*)d_in[17];
  const float* bgg   = (const float*)d_in[18];
  const float* W1    = (const float*)d_in[19];
  const float* b1    = (const float*)d_in[20];
  const float* W2    = (const float*)d_in[21];
  const float* b2    = (const float*)d_in[22];

  float* out_y    = (float*)d_out;
  float* out_gate = out_y + (size_t)B_TOK * E_DIM;
  float* out_loss = out_gate + (size_t)B_TOK * N_EXPC;

  char* p = (char*)d_ws;
  auto alloc = [&](size_t bytes) { char* r = p; p += (bytes + 255) & ~(size_t)255; return r; };
  uint16_t* WencT = (uint16_t*)alloc((size_t)OUT_DIM * IMGSZ * 2);
  uint16_t* WimgT = (uint16_t*)alloc((size_t)OUT_DIM * E_DIM * 2);
  uint16_t* W1T   = (uint16_t*)alloc((size_t)N_EXPC * HID * E_DIM * 2);
  uint16_t* W2T   = (uint16_t*)alloc((size_t)N_EXPC * E_DIM * HID * 2);
  float* g1c  = (float*)alloc((size_t)E_DIM * 8 * 4);
  float* G3   = (float*)alloc((size_t)E_DIM * 8 * 4);
  float* t1   = (float*)alloc(E_DIM * 4);
  float* gbv  = (float*)alloc(64 * 4);
  int*   topIdx = (int*)alloc(B_TOK * 2 * 4);
  float* topW   = (float*)alloc(B_TOK * 2 * 4);
  int*   slotOf = (int*)alloc(B_TOK * 2 * 4);
  int*   counts = (int*)alloc(64 * 4);
  int*   bases  = (int*)alloc(64 * 4);
  int*   cursor = (int*)alloc(64 * 4);
  int*   meta   = (int*)alloc((1 + 3 * (NTIL + 1)) * 4 + 64);
  int*   perm   = (int*)alloc(NSLOT * 4);
  uint16_t* xbf   = (uint16_t*)alloc((size_t)B_TOK * E_DIM * 2);
  uint16_t* Hbuf  = (uint16_t*)alloc((size_t)NSLOT * HID * 2);
  float*    Yg    = (float*)alloc((size_t)NSLOT * E_DIM * 4);
  if ((size_t)(p - (char*)d_ws) > ws_size) return;   // ws too small: fail visibly

  zero_k<<<1, 64, 0, stream>>>(counts, cursor);

  // weight transposes (f32 [R][C] -> bf16 [C][R])
  transpose64<<<dim3(OUT_DIM / 64, IMGSZ / 64, 1), 256, 0, stream>>>(W_enc, WencT, IMGSZ, OUT_DIM);
  transpose64<<<dim3(OUT_DIM / 64, E_DIM / 64, 1), 256, 0, stream>>>(W_img, WimgT, E_DIM, OUT_DIM);
  transpose64<<<dim3(HID / 64, E_DIM / 64, 8), 256, 0, stream>>>(W1, W1T, E_DIM, HID);
  transpose64<<<dim3(E_DIM / 64, HID / 64, 8), 256, 0, stream>>>(W2, W2T, HID, E_DIM);

  // gate fold (f32, precision-critical): logits = text@(Wv@(Wo@Wg)) + ((bv@Wo+bo)@Wg + bg)
  bvwo_k<<<4, 256, 0, stream>>>(bv, Wo, bo, t1);
  g1_k<<<32, 256, 0, stream>>>(Wo, Wg, g1c);
  g2_k<<<32, 256, 0, stream>>>(Wv, g1c, G3);
  gbias_k<<<1, 64, 0, stream>>>(t1, Wg, bgg, gbv);
  gate_k<<<B_TOK, 256, 0, stream>>>(text, G3, gbv, out_gate, topIdx, topW, counts);
  imp_k<<<8, 256, 0, stream>>>(out_gate, t1);
  loss_k<<<1, 64, 0, stream>>>(t1, out_loss);
  scan_k<<<1, 64, 0, stream>>>(counts, bases, meta);
  fill_k<<<16, 256, 0, stream>>>(topIdx, cursor, bases, perm, slotOf);

  // visionFeatures x = [enc(s)|enc(t)|enc(bg)|silu(img@W_img+b)]  (f32-A staged directly)
  gemm_p<64, 1, false, false, true, 1><<<dim3(B_TOK / 128, OUT_DIM / 64, 3), 256, 0, stream>>>(
      src, tgt, bgr, nullptr, IMGSZ, WencT, xbf, E_DIM, b_enc,
      IMGSZ, 0, OUT_DIM, nullptr, nullptr, 0, 0);
  gemm_p<64, 2, false, false, true, 1><<<dim3(B_TOK / 128, OUT_DIM / 64, 1), 256, 0, stream>>>(
      image, nullptr, nullptr, nullptr, E_DIM, WimgT, xbf, E_DIM, b_img,
      E_DIM, 3 * OUT_DIM, 0, nullptr, nullptr, 0, 0);

  // sparse top-2 expert MLPs: 1D supertile-raster grid + XCD swizzle
  gemm_p<128, 3, true, true, false, HID / 128><<<dim3(NTIL * (HID / 128)), 256, 0, stream>>>(
      nullptr, nullptr, nullptr, xbf, E_DIM, W1T, Hbuf, HID, b1,
      E_DIM, 0, 0, meta, perm, (size_t)HID * E_DIM, HID);
  gemm_p<128, 0, false, true, false, E_DIM / 128><<<dim3(NTIL * (E_DIM / 128)), 256, 0, stream>>>(
      nullptr, nullptr, nullptr, Hbuf, HID, W2T, Yg, E_DIM, b2,
      HID, 0, 0, meta, perm, (size_t)E_DIM * HID, E_DIM);

  combine_k<<<B_TOK, 256, 0, stream>>>(Yg, slotOf, topW, out_y);
}